// Round 14
// baseline (738.793 us; speedup 1.0000x reference)
//
#include <hip/hip_runtime.h>
#include <hip/hip_bf16.h>

#define NN 32768
#define DEG 8
#define PW 548          // BigW cols: Mqk1(128) Mqk2(128) qk(36) Mvo1(128) Mvo2(128)
#define GW 676          // G row: h(128) | hMq1 | hMq2 | qk(36) | Go1 | Go2
#define TP 428          // padded LDS tile width for score prefix (420 used)
#define XW 132          // padded xf row stride (16B-aligned rows)

typedef unsigned short u16;
typedef unsigned int u32;

__device__ __forceinline__ float bf2f(u32 lo16) { return __uint_as_float(lo16 << 16); }

// ---------------- dtype detection ----------------
__global__ void detect_kernel(const void* __restrict__ x, int* __restrict__ flagp) {
  if (threadIdx.x == 0) {
    const u16* u = (const u16*)x;
    int insane = 0;
    for (int i = 0; i < 128; ++i) {
      int e = (u[i] >> 7) & 0xff;
      if (e == 0 || e == 0xff || e < 0x70 || e > 0x8f) insane++;
    }
    *flagp = (insane >= 16) ? 0 : 1;   // 1 = bf16 inputs, 0 = f32 inputs
  }
}

// ---------------- input conversion (all 9 arrays, one kernel) ----------------
struct CvtAll {
  const void* src[9];
  float* dst[9];
  int cum[10];          // cumulative element offsets, cum[9] = total
};

__global__ void cvt_all_kernel(CvtAll d, const int* __restrict__ flagp) {
  const int f = *flagp;
  const int total = d.cum[9];
  for (int g = blockIdx.x * 256 + threadIdx.x; g < total; g += gridDim.x * 256) {
    int s = 0;
    #pragma unroll
    for (int k = 1; k < 9; ++k) s += (g >= d.cum[k]);
    const int i = g - d.cum[s];
    float v;
    if (f) v = bf2f((u32)((const u16*)d.src[s])[i]);
    else   v = ((const float*)d.src[s])[i];
    if (s == 0) d.dst[0][(i / 130) * XW + (i % 130)] = v;   // xf padded rows
    else        d.dst[s][i] = v;
  }
}

// ---------------- derived small tables, parallelized ----------------
// cq/ck: grid (5, 4 heads)
__global__ __launch_bounds__(256) void derive_cqck_kernel(
    const float* __restrict__ qw, const float* __restrict__ qb,
    float* __restrict__ cq, float* __restrict__ ck) {
  const int hd = blockIdx.y;
  const float* Wq = qw + (size_t)(hd*3 + 0) * 18769;
  const float* Wk = qw + (size_t)(hd*3 + 1) * 18769;
  const float* bq = qb + (hd*3 + 0) * 137;
  const float* bk = qb + (hd*3 + 1) * 137;
  const int idx = blockIdx.x * 256 + threadIdx.x;
  if (idx >= 1233) return;
  const int s = idx / 137, e = idx % 137;
  cq[hd*1233 + idx] = Wq[e*137 + 128 + s] + bq[e];
  ck[hd*1233 + idx] = Wk[e*137 + 128 + s] + bk[e];
}

// cvo/cc/bo_sum: grid (6, 4 heads); runs after derive_cqck (cc reads cq/ck)
__global__ __launch_bounds__(256) void derive_rest_kernel(
    const float* __restrict__ qw, const float* __restrict__ qb,
    const float* __restrict__ ow, const float* __restrict__ ob,
    const float* __restrict__ cq, const float* __restrict__ ck,
    float* __restrict__ cvo, float* __restrict__ cc, float* __restrict__ bo_sum) {
  const int hd = blockIdx.y;
  const float* Wv = qw + (size_t)(hd*3 + 2) * 18769;
  const float* bv = qb + (hd*3 + 2) * 137;
  const float* Wo = ow + (size_t)hd * 18769;
  const int idx = blockIdx.x * 256 + threadIdx.x;
  if (idx < 1152) {
    const int s = idx >> 7, oi = idx & 127;
    float a = 0.f;
    for (int e = 0; e < 137; ++e) a += Wo[oi*137 + e] * (Wv[e*137 + 128 + s] + bv[e]);
    cvo[hd*1152 + idx] = a;
  } else if (idx < 1233) {
    const int r = idx - 1152, i = r / 9, j = r % 9;
    float a = 0.f;
    for (int e = 0; e < 137; ++e) a += cq[hd*1233 + i*137 + e] * ck[hd*1233 + j*137 + e];
    cc[hd*81 + r] = a;
  } else if (idx < 1361 && (hd & 1) == 0) {
    const int oi = idx - 1233, l = hd >> 1;
    bo_sum[l*128 + oi] = ob[(l*2 + 0)*137 + oi] + ob[(l*2 + 1)*137 + oi];
  }
}

// ---------------- Mqk / Mvo (grid 64 x 4 heads, 1 thread per element) ----------------
__global__ __launch_bounds__(256) void derive_mm_kernel(
    const float* __restrict__ qw, const float* __restrict__ ow,
    float* __restrict__ Mqk, float* __restrict__ Mvo) {
  const int hd = blockIdx.y;
  const float* Wq = qw + (size_t)(hd*3 + 0) * 18769;
  const float* Wk = qw + (size_t)(hd*3 + 1) * 18769;
  const float* Wv = qw + (size_t)(hd*3 + 2) * 18769;
  const float* Wo = ow + (size_t)hd * 18769;
  const int idx = blockIdx.x * 256 + threadIdx.x;   // 0..16383
  const int row = idx >> 7, col = idx & 127;
  float sq = 0.f, so = 0.f;
  #pragma unroll 4
  for (int e = 0; e < 137; ++e) {
    sq += Wq[e*137 + row] * Wk[e*137 + col];     // Mqk[c][c']
    so += Wo[row*137 + e] * Wv[e*137 + col];     // Mvo[oi][c]
  }
  Mqk[hd*16384 + idx] = sq;
  Mvo[hd*16384 + idx] = so;
}

// BigW[l][k][col], 128 x PW per layer
// layout: [0..127]=Mqk1  [128..255]=Mqk2  [256..291]=qk  [292..419]=Mvo1  [420..547]=Mvo2
__global__ void bigw_kernel(const float* __restrict__ qw,
                            const float* __restrict__ Mqk, const float* __restrict__ Mvo,
                            const float* __restrict__ cq, const float* __restrict__ ck,
                            float* __restrict__ BigW) {
  const int idx = blockIdx.x * 256 + threadIdx.x;
  if (idx >= 2 * 128 * PW) return;
  const int l = idx / (128 * PW);
  const int r = idx % (128 * PW);
  const int k = r / PW, col = r % PW;
  float v = 0.f;
  if (col < 128)       v = Mqk[(l*2 + 0)*16384 + k*128 + col];
  else if (col < 256)  v = Mqk[(l*2 + 1)*16384 + k*128 + (col - 128)];
  else if (col < 274) {                       // qk_q: Hq_t . ck[t][j], linear in h
    int q = col - 256, t = q / 9, j = q % 9;
    const float* Wq = qw + (size_t)((l*2 + t)*3 + 0) * 18769;
    const float* ckp = ck + (l*2 + t)*1233 + j*137;
    float a = 0.f;
    for (int e = 0; e < 137; ++e) a += Wq[e*137 + k] * ckp[e];
    v = a;
  } else if (col < 292) {                     // qk_k: cq[t][i] . Hk_t
    int q = col - 274, t = q / 9, i = q % 9;
    const float* Wk_ = qw + (size_t)((l*2 + t)*3 + 1) * 18769;
    const float* cqp = cq + (l*2 + t)*1233 + i*137;
    float a = 0.f;
    for (int e = 0; e < 137; ++e) a += cqp[e] * Wk_[e*137 + k];
    v = a;
  }
  else if (col < 420)  v = Mvo[(l*2 + 0)*16384 + (col - 292)*128 + k];
  else                 v = Mvo[(l*2 + 1)*16384 + (col - 420)*128 + k];
  BigW[idx] = v;
}

// ---------------- BigB[l] = [ W_l | W_l @ BigW_l ]  (Kl x 676) ----------------
__global__ __launch_bounds__(256) void buildb_kernel(
    const float* __restrict__ W1, const float* __restrict__ W2,
    const float* __restrict__ BigW, float* __restrict__ BigB) {
  const int l = blockIdx.y;
  const int Kl = l ? 128 : 130;
  const float* W = l ? W2 : W1;
  const int idx = blockIdx.x * 256 + threadIdx.x;
  if (idx >= Kl * 676) return;
  const int k = idx / 676, c = idx % 676;
  float v;
  if (c < 128) {
    v = W[k * 128 + c];
  } else {
    const int c2 = c - 128;
    const float* Wk = W + k * 128;
    const float* Bc = BigW + (size_t)l * 128 * PW + c2;
    float a = 0.f;
    #pragma unroll 4
    for (int m = 0; m < 128; ++m) a += Wk[m] * Bc[(size_t)m * PW];
    v = a;
  }
  BigB[(size_t)l * 130 * 676 + (size_t)k * 676 + c] = v;
}

// ---------------- 128x128-tile f32 GEMM, register-prefetch pipelined ----------------
// C = op(A)(MxK) @ B(KxNC), runtime K. Ragged col tile handled by guards.
// REGISTER-PRESSURE HAZARD (R10/R12/R13): this kernel lives at ~105 VGPR.
// No __launch_bounds__ min-waves clamp, no compile-time trip count, and the
// outer loop is pinned with `#pragma unroll 1` — any unrolling keeps extra
// prefetch generations live, spills acc (or starves occupancy), 2-90x loss.
// If astats != null: a_elem = relu((a_elem - astats[k]) * astats[128])
__global__ __launch_bounds__(256) void gemm128_kernel(
    const float* __restrict__ A, const float* __restrict__ B,
    float* __restrict__ C,
    int M, int K, int NC, int lda, int ldb, int ldc,
    const float* __restrict__ astats) {
  __shared__ float As[16][128];   // k-major: fragment reads broadcast
  __shared__ float Bs[16][132];
  const int tid = threadIdx.x;
  const int row0 = blockIdx.y * 128, col0 = blockIdx.x * 128;
  const int tx = tid & 15, ty = tid >> 4;
  const float ainv = astats ? astats[128] : 1.f;
  const int ar = tid >> 1, aq = (tid & 1) * 8;   // A staging: row, k-octet
  const int bk = tid >> 4, bc = (tid & 15) * 8;  // B staging: k, col-octet
  const float* Arow = A + (size_t)(row0 + ar) * lda + aq;
  const float* Bcol = B + (size_t)bk * ldb + col0 + bc;
  float av[8], bv[8];
  float acc[8][8] = {};
  const int nsteps = (K + 15) / 16;

  auto loadA = [&](int k0) {
    const float* Ap = Arow + k0;
    if (k0 + 16 <= K) {
      const float4 v0 = *(const float4*)Ap;
      const float4 v1 = *(const float4*)(Ap + 4);
      av[0]=v0.x; av[1]=v0.y; av[2]=v0.z; av[3]=v0.w;
      av[4]=v1.x; av[5]=v1.y; av[6]=v1.z; av[7]=v1.w;
    } else {
      #pragma unroll
      for (int p = 0; p < 8; ++p) av[p] = (k0 + aq + p < K) ? Ap[p] : 0.f;
    }
    if (astats) {
      #pragma unroll
      for (int p = 0; p < 8; ++p) {
        const int kc = k0 + aq + p;
        if (kc < K) av[p] = fmaxf((av[p] - astats[kc]) * ainv, 0.f);
      }
    }
  };
  auto loadB = [&](int k0) {
    const int kg = k0 + bk;
    const float* Bp = Bcol + (size_t)k0 * ldb;
    if (kg < K && col0 + bc + 8 <= NC) {
      const float4 v0 = *(const float4*)Bp;
      const float4 v1 = *(const float4*)(Bp + 4);
      bv[0]=v0.x; bv[1]=v0.y; bv[2]=v0.z; bv[3]=v0.w;
      bv[4]=v1.x; bv[5]=v1.y; bv[6]=v1.z; bv[7]=v1.w;
    } else {
      #pragma unroll
      for (int p = 0; p < 8; ++p)
        bv[p] = (kg < K && col0 + bc + p < NC) ? Bp[p] : 0.f;
    }
  };

  loadA(0); loadB(0);
  #pragma unroll 1
  for (int step = 0; step < nsteps; ++step) {
    #pragma unroll
    for (int p = 0; p < 8; ++p) As[aq + p][ar] = av[p];
    *(float4*)&Bs[bk][bc]     = make_float4(bv[0], bv[1], bv[2], bv[3]);
    *(float4*)&Bs[bk][bc + 4] = make_float4(bv[4], bv[5], bv[6], bv[7]);
    __syncthreads();
    if (step + 1 < nsteps) { loadA((step + 1) * 16); loadB((step + 1) * 16); }
    #pragma unroll
    for (int kk = 0; kk < 16; ++kk) {
      float a[8], b[8];
      *(float4*)&a[0] = *(const float4*)&As[kk][ty * 8];
      *(float4*)&a[4] = *(const float4*)&As[kk][ty * 8 + 4];
      *(float4*)&b[0] = *(const float4*)&Bs[kk][tx * 8];
      *(float4*)&b[4] = *(const float4*)&Bs[kk][tx * 8 + 4];
      #pragma unroll
      for (int i = 0; i < 8; ++i)
        #pragma unroll
        for (int j = 0; j < 8; ++j)
          acc[i][j] += a[i] * b[j];
    }
    __syncthreads();
  }
  #pragma unroll
  for (int i = 0; i < 8; ++i) {
    const int rr = row0 + ty * 8 + i;
    float* Cp = C + (size_t)rr * ldc + col0 + tx * 8;
    if (col0 + tx * 8 + 8 <= NC) {
      *(float4*)Cp       = make_float4(acc[i][0], acc[i][1], acc[i][2], acc[i][3]);
      *(float4*)(Cp + 4) = make_float4(acc[i][4], acc[i][5], acc[i][6], acc[i][7]);
    } else {
      #pragma unroll
      for (int j = 0; j < 8; ++j)
        if (col0 + tx * 8 + j < NC) Cp[j] = acc[i][j];
    }
  }
}

// ---------------- per-node fused attention (R5 structure: minimal LDS) ----------------
// G row: [0..127]=h  [128..255]=hMq1  [256..383]=hMq2  [384..401]=qkq(t,j)
//        [402..419]=qkk(t,i)  [420..547]=Go1  [548..675]=Go2
__global__ __launch_bounds__(256) void attn_kernel(
    const int* __restrict__ src, const float* __restrict__ G,
    const float* __restrict__ cvo, const float* __restrict__ cc,
    const float* __restrict__ bo_sum, const float* __restrict__ b_layer,
    int layer, float* __restrict__ res) {
  __shared__ float T[9][TP];          // score-feeding prefix of each slot
  __shared__ float As[2][9][9];
  __shared__ float ymax[2][128];
  __shared__ int nbr[9];
  const int n = blockIdx.x;
  const int tid = threadIdx.x;
  if (tid < 9) nbr[tid] = (tid < 8) ? src[n * DEG + tid] : n;
  __syncthreads();
  // gather: 9 slots x 105 float4 (cols 0..419)
  for (int it = tid; it < 9 * 105; it += 256) {
    const int s = it / 105, w = it % 105;
    *(float4*)&T[s][w * 4] = *(const float4*)(G + (size_t)nbr[s] * GW + w * 4);
  }
  __syncthreads();
  // scores: 162 = 2 heads x 81 pairs
  if (tid < 162) {
    const int t = tid / 81, r = tid % 81, i = r / 9, j = r % 9;
    const float* hm = &T[i][128 + t * 128];
    const float* hj = &T[j][0];
    float s = 0.f;
    #pragma unroll 8
    for (int c = 0; c < 128; c += 4) {
      const float4 a = *(const float4*)&hm[c];
      const float4 b = *(const float4*)&hj[c];
      s += a.x * b.x + a.y * b.y + a.z * b.z + a.w * b.w;
    }
    s += T[i][384 + t*9 + j] + T[j][402 + t*9 + i] + cc[(layer*2 + t)*81 + r];
    As[t][i][j] = s * 0.08543576577f;   // 1/sqrt(137)
  }
  __syncthreads();
  if (tid < 18) {
    const int t = tid / 9, i = tid % 9;
    float* row = &As[t][i][0];
    float m = -3e38f;
    #pragma unroll
    for (int j = 0; j < 9; ++j) m = fmaxf(m, row[j]);
    float ex[9], ssum = 0.f;
    #pragma unroll
    for (int j = 0; j < 9; ++j) { ex[j] = expf(row[j] - m); ssum += ex[j]; }
    const float inv = 1.f / ssum;
    #pragma unroll
    for (int j = 0; j < 9; ++j) row[j] = ex[j] * inv;
  }
  __syncthreads();
  // PV + max: Go read directly from global (coalesced column chunks)
  {
    const int oi = tid & 127, half = tid >> 7;
    const float* cvo1 = cvo + (layer * 2 + 0) * 1152 + oi;
    const float* cvo2 = cvo + (layer * 2 + 1) * 1152 + oi;
    float vg1[9], vg2[9];
    #pragma unroll
    for (int j = 0; j < 9; ++j) {
      const float* gr = G + (size_t)nbr[j] * GW + oi;
      vg1[j] = gr[420] + cvo1[j * 128];
      vg2[j] = gr[548] + cvo2[j * 128];
    }
    float mx = -3e38f;
    const int i0 = half ? 5 : 0, i1 = half ? 9 : 5;
    for (int i = i0; i < i1; ++i) {
      float y = T[i][oi];
      #pragma unroll
      for (int j = 0; j < 9; ++j)
        y += As[0][i][j] * vg1[j] + As[1][i][j] * vg2[j];
      mx = fmaxf(mx, y);
    }
    ymax[half][oi] = mx;
  }
  __syncthreads();
  if (tid < 128) {
    const float v = fmaxf(ymax[0][tid], ymax[1][tid]) + bo_sum[layer*128 + tid] + b_layer[tid];
    res[(size_t)n * 128 + tid] = v;
  }
}

// ---------------- pairnorm reductions ----------------
__global__ __launch_bounds__(256) void reduce_kernel(const float* __restrict__ res,
                                                     float* __restrict__ partial) {
  __shared__ float col2[128];
  __shared__ float sqs[256];
  const int b = blockIdx.x, tid = threadIdx.x;
  const int c = tid & 127, half = tid >> 7;
  float cs = 0.f, sq = 0.f;
  const int r0 = half * 64;
  for (int r = r0; r < r0 + 64; ++r) {
    const float v = res[((size_t)b * 128 + r) * 128 + c];
    cs += v; sq += v * v;
  }
  if (half) col2[c] = cs;
  sqs[tid] = sq;
  __syncthreads();
  if (!half) partial[b * 129 + c] = cs + col2[c];
  for (int s = 128; s >= 1; s >>= 1) {
    if (tid < s) sqs[tid] += sqs[tid + s];
    __syncthreads();
  }
  if (tid == 0) partial[b * 129 + 128] = sqs[0];
}

__global__ __launch_bounds__(1024) void finalize_kernel(const float* __restrict__ partial,
                                                        float* __restrict__ stats) {
  __shared__ float colsum[8][128];
  __shared__ float sqred[256];
  __shared__ float musq[128];
  const int tid = threadIdx.x;
  const int c = tid & 127, g = tid >> 7;
  float cs = 0.f;
  #pragma unroll 8
  for (int b = g * 32; b < g * 32 + 32; ++b) cs += partial[b * 129 + c];
  colsum[g][c] = cs;
  if (tid < 256) sqred[tid] = partial[tid * 129 + 128];
  __syncthreads();
  if (tid < 128) {
    float m = 0.f;
    #pragma unroll
    for (int g2 = 0; g2 < 8; ++g2) m += colsum[g2][tid];
    m *= (1.f / 32768.f);
    stats[tid] = m;
    musq[tid] = m * m;
  }
  __syncthreads();
  for (int s = 128; s >= 1; s >>= 1) {
    if (tid < s) sqred[tid] += sqred[tid + s];
    if (s <= 64 && tid < s) musq[tid] += musq[tid + s];
    __syncthreads();
  }
  if (tid == 0) {
    const float var = sqred[0] * (1.f / 32768.f) - musq[0];
    stats[128] = 1.f / sqrtf(1e-6f + var);
  }
}

__global__ void final_kernel(const float* __restrict__ res, const float* __restrict__ stats,
                             const float* __restrict__ xf, void* __restrict__ out,
                             const int* __restrict__ flagp) {
  const int idx = blockIdx.x * 256 + threadIdx.x;
  const int nrow = idx >> 7, c = idx & 127;
  float v = fmaxf((res[idx] - stats[c]) * stats[128], 0.f);
  v += xf[(size_t)nrow * XW + c];
  if (c == 127 && (v > 1.f || v < -1.f)) v = 0.f;
  v *= 0.5f;
  if (*flagp) ((__hip_bfloat16*)out)[idx] = __float2bfloat16(v);
  else        ((float*)out)[idx] = v;
}

// ---------------- host ----------------
extern "C" void kernel_launch(void* const* d_in, const int* in_sizes, int n_in,
                              void* d_out, int out_size, void* d_ws, size_t ws_size,
                              hipStream_t stream) {
  (void)in_sizes; (void)n_in; (void)out_size; (void)ws_size;
  char* ws = (char*)d_ws;
  size_t off = 0;
  auto alloc = [&](size_t bytes) -> char* {
    char* p = ws + off;
    off += (bytes + 255) & ~(size_t)255;
    return p;
  };
  int*   flagp = (int*)  alloc(4);
  float* xf    = (float*)alloc((size_t)NN * XW * 4);
  float* W1f   = (float*)alloc(130 * 128 * 4);
  float* b1f   = (float*)alloc(128 * 4);
  float* W2f   = (float*)alloc(128 * 128 * 4);
  float* b2f   = (float*)alloc(128 * 4);
  float* qwf   = (float*)alloc((size_t)225228 * 4);
  float* qbf   = (float*)alloc(1644 * 4);
  float* owf   = (float*)alloc((size_t)75076 * 4);
  float* obf   = (float*)alloc(548 * 4);
  float* Mqk   = (float*)alloc((size_t)4 * 16384 * 4);
  float* Mvo   = (float*)alloc((size_t)4 * 16384 * 4);
  float* cq    = (float*)alloc((size_t)4 * 1233 * 4);
  float* ck    = (float*)alloc((size_t)4 * 1233 * 4);
  float* cvo   = (float*)alloc((size_t)4 * 1152 * 4);
  float* cc    = (float*)alloc((size_t)4 * 81 * 4);
  float* boS   = (float*)alloc((size_t)2 * 128 * 4);
  float* BigW  = (float*)alloc((size_t)2 * 128 * PW * 4);
  float* BigB  = (float*)alloc((size_t)2 * 130 * 676 * 4);
  float* G     = (float*)alloc((size_t)NN * GW * 4);
  float* res   = (float*)alloc((size_t)NN * 128 * 4);
  float* part  = (float*)alloc((size_t)256 * 129 * 4);
  float* st0   = (float*)alloc(132 * 4);
  float* st1   = (float*)alloc(132 * 4);

  const int* edge = (const int*)d_in[1];   // row 0 = src

  detect_kernel<<<1, 64, 0, stream>>>(d_in[0], flagp);

  CvtAll ca;
  {
    const int srcidx[9] = {0, 2, 3, 4, 5, 6, 7, 8, 9};
    float* dsts[9] = {xf, W1f, b1f, W2f, b2f, qwf, qbf, owf, obf};
    const int ns[9] = {NN * 130, 130 * 128, 128, 128 * 128, 128,
                       225228, 1644, 75076, 548};
    int acc = 0;
    for (int i = 0; i < 9; ++i) {
      ca.src[i] = d_in[srcidx[i]];
      ca.dst[i] = dsts[i];
      ca.cum[i] = acc;
      acc += ns[i];
    }
    ca.cum[9] = acc;
  }
  cvt_all_kernel<<<4096, 256, 0, stream>>>(ca, flagp);

  derive_cqck_kernel<<<dim3(5, 4), 256, 0, stream>>>(qwf, qbf, cq, ck);
  derive_rest_kernel<<<dim3(6, 4), 256, 0, stream>>>(qwf, qbf, owf, obf, cq, ck,
                                                     cvo, cc, boS);
  derive_mm_kernel<<<dim3(64, 4), 256, 0, stream>>>(qwf, owf, Mqk, Mvo);
  bigw_kernel<<<(2 * 128 * PW + 255) / 256, 256, 0, stream>>>(qwf, Mqk, Mvo, cq, ck, BigW);
  buildb_kernel<<<dim3((130 * 676 + 255) / 256, 2), 256, 0, stream>>>(W1f, W2f, BigW, BigB);

  for (int l = 0; l < 2; ++l) {
    // G = op(act) @ BigB_l  (single ragged GEMM; pairnorm+relu folded into A for l=1)
    if (l == 0) {
      gemm128_kernel<<<dim3(6, NN / 128), 256, 0, stream>>>(
          xf, BigB, G, NN, 130, GW, XW, 676, GW, nullptr);
    } else {
      gemm128_kernel<<<dim3(6, NN / 128), 256, 0, stream>>>(
          res, BigB + (size_t)130 * 676, G, NN, 128, GW, 128, 676, GW, st0);
    }
    // fused per-node attention + max + bias
    attn_kernel<<<NN, 256, 0, stream>>>(edge, G, cvo, cc, boS,
                                        l ? b2f : b1f, l, res);
    // pairnorm stats
    reduce_kernel<<<256, 256, 0, stream>>>(res, part);
    finalize_kernel<<<1, 1024, 0, stream>>>(part, l ? st1 : st0);
  }
  final_kernel<<<NN * 128 / 256, 256, 0, stream>>>(res, st1, xf, d_out, flagp);
}

// Round 15
// 615.897 us; speedup vs baseline: 1.1995x; 1.1995x over previous
//
#include <hip/hip_runtime.h>
#include <hip/hip_bf16.h>

#define NN 32768
#define DEG 8
#define PW 548          // BigW cols: Mqk1(128) Mqk2(128) qk(36) Mvo1(128) Mvo2(128)
#define GW 676          // G row: h(128) | hMq1 | hMq2 | qk(36) | Go1 | Go2
#define TP 428          // padded LDS tile width for score prefix (420 used)
#define XW 132          // padded xf row stride (16B-aligned rows)

typedef unsigned short u16;
typedef unsigned int u32;

__device__ __forceinline__ float bf2f(u32 lo16) { return __uint_as_float(lo16 << 16); }

// ---------------- dtype detection ----------------
__global__ void detect_kernel(const void* __restrict__ x, int* __restrict__ flagp) {
  if (threadIdx.x == 0) {
    const u16* u = (const u16*)x;
    int insane = 0;
    for (int i = 0; i < 128; ++i) {
      int e = (u[i] >> 7) & 0xff;
      if (e == 0 || e == 0xff || e < 0x70 || e > 0x8f) insane++;
    }
    *flagp = (insane >= 16) ? 0 : 1;   // 1 = bf16 inputs, 0 = f32 inputs
  }
}

// ---------------- input conversion (all 9 arrays, one kernel) ----------------
struct CvtAll {
  const void* src[9];
  float* dst[9];
  int cum[10];          // cumulative element offsets, cum[9] = total
};

__global__ void cvt_all_kernel(CvtAll d, const int* __restrict__ flagp) {
  const int f = *flagp;
  const int total = d.cum[9];
  for (int g = blockIdx.x * 256 + threadIdx.x; g < total; g += gridDim.x * 256) {
    int s = 0;
    #pragma unroll
    for (int k = 1; k < 9; ++k) s += (g >= d.cum[k]);
    const int i = g - d.cum[s];
    float v;
    if (f) v = bf2f((u32)((const u16*)d.src[s])[i]);
    else   v = ((const float*)d.src[s])[i];
    if (s == 0) d.dst[0][(i / 130) * XW + (i % 130)] = v;   // xf padded rows
    else        d.dst[s][i] = v;
  }
}

// ---------------- derived small tables, parallelized ----------------
// cq/ck: grid (5, 4 heads)
__global__ __launch_bounds__(256) void derive_cqck_kernel(
    const float* __restrict__ qw, const float* __restrict__ qb,
    float* __restrict__ cq, float* __restrict__ ck) {
  const int hd = blockIdx.y;
  const float* Wq = qw + (size_t)(hd*3 + 0) * 18769;
  const float* Wk = qw + (size_t)(hd*3 + 1) * 18769;
  const float* bq = qb + (hd*3 + 0) * 137;
  const float* bk = qb + (hd*3 + 1) * 137;
  const int idx = blockIdx.x * 256 + threadIdx.x;
  if (idx >= 1233) return;
  const int s = idx / 137, e = idx % 137;
  cq[hd*1233 + idx] = Wq[e*137 + 128 + s] + bq[e];
  ck[hd*1233 + idx] = Wk[e*137 + 128 + s] + bk[e];
}

// cvo/cc/bo_sum: grid (6, 4 heads); runs after derive_cqck (cc reads cq/ck)
__global__ __launch_bounds__(256) void derive_rest_kernel(
    const float* __restrict__ qw, const float* __restrict__ qb,
    const float* __restrict__ ow, const float* __restrict__ ob,
    const float* __restrict__ cq, const float* __restrict__ ck,
    float* __restrict__ cvo, float* __restrict__ cc, float* __restrict__ bo_sum) {
  const int hd = blockIdx.y;
  const float* Wv = qw + (size_t)(hd*3 + 2) * 18769;
  const float* bv = qb + (hd*3 + 2) * 137;
  const float* Wo = ow + (size_t)hd * 18769;
  const int idx = blockIdx.x * 256 + threadIdx.x;
  if (idx < 1152) {
    const int s = idx >> 7, oi = idx & 127;
    float a = 0.f;
    for (int e = 0; e < 137; ++e) a += Wo[oi*137 + e] * (Wv[e*137 + 128 + s] + bv[e]);
    cvo[hd*1152 + idx] = a;
  } else if (idx < 1233) {
    const int r = idx - 1152, i = r / 9, j = r % 9;
    float a = 0.f;
    for (int e = 0; e < 137; ++e) a += cq[hd*1233 + i*137 + e] * ck[hd*1233 + j*137 + e];
    cc[hd*81 + r] = a;
  } else if (idx < 1361 && (hd & 1) == 0) {
    const int oi = idx - 1233, l = hd >> 1;
    bo_sum[l*128 + oi] = ob[(l*2 + 0)*137 + oi] + ob[(l*2 + 1)*137 + oi];
  }
}

// ---------------- Mqk / Mvo (grid 64 x 4 heads, 1 thread per element) ----------------
__global__ __launch_bounds__(256) void derive_mm_kernel(
    const float* __restrict__ qw, const float* __restrict__ ow,
    float* __restrict__ Mqk, float* __restrict__ Mvo) {
  const int hd = blockIdx.y;
  const float* Wq = qw + (size_t)(hd*3 + 0) * 18769;
  const float* Wk = qw + (size_t)(hd*3 + 1) * 18769;
  const float* Wv = qw + (size_t)(hd*3 + 2) * 18769;
  const float* Wo = ow + (size_t)hd * 18769;
  const int idx = blockIdx.x * 256 + threadIdx.x;   // 0..16383
  const int row = idx >> 7, col = idx & 127;
  float sq = 0.f, so = 0.f;
  #pragma unroll 4
  for (int e = 0; e < 137; ++e) {
    sq += Wq[e*137 + row] * Wk[e*137 + col];     // Mqk[c][c']
    so += Wo[row*137 + e] * Wv[e*137 + col];     // Mvo[oi][c]
  }
  Mqk[hd*16384 + idx] = sq;
  Mvo[hd*16384 + idx] = so;
}

// BigW[l][k][col], 128 x PW per layer
// layout: [0..127]=Mqk1  [128..255]=Mqk2  [256..291]=qk  [292..419]=Mvo1  [420..547]=Mvo2
__global__ void bigw_kernel(const float* __restrict__ qw,
                            const float* __restrict__ Mqk, const float* __restrict__ Mvo,
                            const float* __restrict__ cq, const float* __restrict__ ck,
                            float* __restrict__ BigW) {
  const int idx = blockIdx.x * 256 + threadIdx.x;
  if (idx >= 2 * 128 * PW) return;
  const int l = idx / (128 * PW);
  const int r = idx % (128 * PW);
  const int k = r / PW, col = r % PW;
  float v = 0.f;
  if (col < 128)       v = Mqk[(l*2 + 0)*16384 + k*128 + col];
  else if (col < 256)  v = Mqk[(l*2 + 1)*16384 + k*128 + (col - 128)];
  else if (col < 274) {                       // qk_q: Hq_t . ck[t][j], linear in h
    int q = col - 256, t = q / 9, j = q % 9;
    const float* Wq = qw + (size_t)((l*2 + t)*3 + 0) * 18769;
    const float* ckp = ck + (l*2 + t)*1233 + j*137;
    float a = 0.f;
    for (int e = 0; e < 137; ++e) a += Wq[e*137 + k] * ckp[e];
    v = a;
  } else if (col < 292) {                     // qk_k: cq[t][i] . Hk_t
    int q = col - 274, t = q / 9, i = q % 9;
    const float* Wk_ = qw + (size_t)((l*2 + t)*3 + 1) * 18769;
    const float* cqp = cq + (l*2 + t)*1233 + i*137;
    float a = 0.f;
    for (int e = 0; e < 137; ++e) a += cqp[e] * Wk_[e*137 + k];
    v = a;
  }
  else if (col < 420)  v = Mvo[(l*2 + 0)*16384 + (col - 292)*128 + k];
  else                 v = Mvo[(l*2 + 1)*16384 + (col - 420)*128 + k];
  BigW[idx] = v;
}

// ---------------- BigB[l] = [ W_l | W_l @ BigW_l ]  (Kl x 676) ----------------
__global__ __launch_bounds__(256) void buildb_kernel(
    const float* __restrict__ W1, const float* __restrict__ W2,
    const float* __restrict__ BigW, float* __restrict__ BigB) {
  const int l = blockIdx.y;
  const int Kl = l ? 128 : 130;
  const float* W = l ? W2 : W1;
  const int idx = blockIdx.x * 256 + threadIdx.x;
  if (idx >= Kl * 676) return;
  const int k = idx / 676, c = idx % 676;
  float v;
  if (c < 128) {
    v = W[k * 128 + c];
  } else {
    const int c2 = c - 128;
    const float* Wk = W + k * 128;
    const float* Bc = BigW + (size_t)l * 128 * PW + c2;
    float a = 0.f;
    #pragma unroll 4
    for (int m = 0; m < 128; ++m) a += Wk[m] * Bc[(size_t)m * PW];
    v = a;
  }
  BigB[(size_t)l * 130 * 676 + (size_t)k * 676 + c] = v;
}

// ---------------- 128x128-tile f32 GEMM, register-prefetch pipelined ----------------
// EXACT R9 TEXT (measured-fast). REGISTER-PRESSURE HAZARD (R10/R12/R13/R14):
// do NOT hoist base pointers out of the load lambdas, do NOT add launch_bounds
// min-waves, do NOT make K compile-time, do NOT add unroll pragmas to the
// outer loop. Every one of those pushed VGPR 105 -> 140-256 (spill or
// occupancy starvation, 1.7x-90x regression).
// If astats != null: a_elem = relu((a_elem - astats[k]) * astats[128])
__global__ __launch_bounds__(256) void gemm128_kernel(
    const float* __restrict__ A, const float* __restrict__ B,
    float* __restrict__ C,
    int M, int K, int NC, int lda, int ldb, int ldc,
    const float* __restrict__ astats) {
  __shared__ float As[16][128];   // k-major: fragment reads broadcast
  __shared__ float Bs[16][132];
  const int tid = threadIdx.x;
  const int row0 = blockIdx.y * 128, col0 = blockIdx.x * 128;
  const int tx = tid & 15, ty = tid >> 4;
  const float ainv = astats ? astats[128] : 1.f;
  const int ar = tid >> 1, aq = (tid & 1) * 8;   // A staging: row, k-octet
  const int bk = tid >> 4, bc = (tid & 15) * 8;  // B staging: k, col-octet
  float av[8], bv[8];
  float acc[8][8] = {};
  const int nsteps = (K + 15) / 16;

  auto loadA = [&](int k0) {
    const float* Ap = A + (size_t)(row0 + ar) * lda + k0 + aq;
    if (k0 + 16 <= K) {
      const float4 v0 = *(const float4*)Ap;
      const float4 v1 = *(const float4*)(Ap + 4);
      av[0]=v0.x; av[1]=v0.y; av[2]=v0.z; av[3]=v0.w;
      av[4]=v1.x; av[5]=v1.y; av[6]=v1.z; av[7]=v1.w;
    } else {
      #pragma unroll
      for (int p = 0; p < 8; ++p) av[p] = (k0 + aq + p < K) ? Ap[p] : 0.f;
    }
    if (astats) {
      #pragma unroll
      for (int p = 0; p < 8; ++p) {
        const int kc = k0 + aq + p;
        if (kc < K) av[p] = fmaxf((av[p] - astats[kc]) * ainv, 0.f);
      }
    }
  };
  auto loadB = [&](int k0) {
    const int kg = k0 + bk;
    const float* Bp = B + (size_t)kg * ldb + col0 + bc;
    if (kg < K && col0 + bc + 8 <= NC) {
      const float4 v0 = *(const float4*)Bp;
      const float4 v1 = *(const float4*)(Bp + 4);
      bv[0]=v0.x; bv[1]=v0.y; bv[2]=v0.z; bv[3]=v0.w;
      bv[4]=v1.x; bv[5]=v1.y; bv[6]=v1.z; bv[7]=v1.w;
    } else {
      #pragma unroll
      for (int p = 0; p < 8; ++p)
        bv[p] = (kg < K && col0 + bc + p < NC) ? Bp[p] : 0.f;
    }
  };

  loadA(0); loadB(0);
  for (int step = 0; step < nsteps; ++step) {
    #pragma unroll
    for (int p = 0; p < 8; ++p) As[aq + p][ar] = av[p];
    *(float4*)&Bs[bk][bc]     = make_float4(bv[0], bv[1], bv[2], bv[3]);
    *(float4*)&Bs[bk][bc + 4] = make_float4(bv[4], bv[5], bv[6], bv[7]);
    __syncthreads();
    if (step + 1 < nsteps) { loadA((step + 1) * 16); loadB((step + 1) * 16); }
    #pragma unroll
    for (int kk = 0; kk < 16; ++kk) {
      float a[8], b[8];
      *(float4*)&a[0] = *(const float4*)&As[kk][ty * 8];
      *(float4*)&a[4] = *(const float4*)&As[kk][ty * 8 + 4];
      *(float4*)&b[0] = *(const float4*)&Bs[kk][tx * 8];
      *(float4*)&b[4] = *(const float4*)&Bs[kk][tx * 8 + 4];
      #pragma unroll
      for (int i = 0; i < 8; ++i)
        #pragma unroll
        for (int j = 0; j < 8; ++j)
          acc[i][j] += a[i] * b[j];
    }
    __syncthreads();
  }
  #pragma unroll
  for (int i = 0; i < 8; ++i) {
    const int rr = row0 + ty * 8 + i;
    float* Cp = C + (size_t)rr * ldc + col0 + tx * 8;
    if (col0 + tx * 8 + 8 <= NC) {
      *(float4*)Cp       = make_float4(acc[i][0], acc[i][1], acc[i][2], acc[i][3]);
      *(float4*)(Cp + 4) = make_float4(acc[i][4], acc[i][5], acc[i][6], acc[i][7]);
    } else {
      #pragma unroll
      for (int j = 0; j < 8; ++j)
        if (col0 + tx * 8 + j < NC) Cp[j] = acc[i][j];
    }
  }
}

// ---------------- per-node fused attention (R5 structure: minimal LDS) ----------------
// G row: [0..127]=h  [128..255]=hMq1  [256..383]=hMq2  [384..401]=qkq(t,j)
//        [402..419]=qkk(t,i)  [420..547]=Go1  [548..675]=Go2
__global__ __launch_bounds__(256) void attn_kernel(
    const int* __restrict__ src, const float* __restrict__ G,
    const float* __restrict__ cvo, const float* __restrict__ cc,
    const float* __restrict__ bo_sum, const float* __restrict__ b_layer,
    int layer, float* __restrict__ res) {
  __shared__ float T[9][TP];          // score-feeding prefix of each slot
  __shared__ float As[2][9][9];
  __shared__ float ymax[2][128];
  __shared__ int nbr[9];
  const int n = blockIdx.x;
  const int tid = threadIdx.x;
  if (tid < 9) nbr[tid] = (tid < 8) ? src[n * DEG + tid] : n;
  __syncthreads();
  // gather: 9 slots x 105 float4 (cols 0..419)
  for (int it = tid; it < 9 * 105; it += 256) {
    const int s = it / 105, w = it % 105;
    *(float4*)&T[s][w * 4] = *(const float4*)(G + (size_t)nbr[s] * GW + w * 4);
  }
  __syncthreads();
  // scores: 162 = 2 heads x 81 pairs
  if (tid < 162) {
    const int t = tid / 81, r = tid % 81, i = r / 9, j = r % 9;
    const float* hm = &T[i][128 + t * 128];
    const float* hj = &T[j][0];
    float s = 0.f;
    #pragma unroll 8
    for (int c = 0; c < 128; c += 4) {
      const float4 a = *(const float4*)&hm[c];
      const float4 b = *(const float4*)&hj[c];
      s += a.x * b.x + a.y * b.y + a.z * b.z + a.w * b.w;
    }
    s += T[i][384 + t*9 + j] + T[j][402 + t*9 + i] + cc[(layer*2 + t)*81 + r];
    As[t][i][j] = s * 0.08543576577f;   // 1/sqrt(137)
  }
  __syncthreads();
  if (tid < 18) {
    const int t = tid / 9, i = tid % 9;
    float* row = &As[t][i][0];
    float m = -3e38f;
    #pragma unroll
    for (int j = 0; j < 9; ++j) m = fmaxf(m, row[j]);
    float ex[9], ssum = 0.f;
    #pragma unroll
    for (int j = 0; j < 9; ++j) { ex[j] = expf(row[j] - m); ssum += ex[j]; }
    const float inv = 1.f / ssum;
    #pragma unroll
    for (int j = 0; j < 9; ++j) row[j] = ex[j] * inv;
  }
  __syncthreads();
  // PV + max: Go read directly from global (coalesced column chunks)
  {
    const int oi = tid & 127, half = tid >> 7;
    const float* cvo1 = cvo + (layer * 2 + 0) * 1152 + oi;
    const float* cvo2 = cvo + (layer * 2 + 1) * 1152 + oi;
    float vg1[9], vg2[9];
    #pragma unroll
    for (int j = 0; j < 9; ++j) {
      const float* gr = G + (size_t)nbr[j] * GW + oi;
      vg1[j] = gr[420] + cvo1[j * 128];
      vg2[j] = gr[548] + cvo2[j * 128];
    }
    float mx = -3e38f;
    const int i0 = half ? 5 : 0, i1 = half ? 9 : 5;
    for (int i = i0; i < i1; ++i) {
      float y = T[i][oi];
      #pragma unroll
      for (int j = 0; j < 9; ++j)
        y += As[0][i][j] * vg1[j] + As[1][i][j] * vg2[j];
      mx = fmaxf(mx, y);
    }
    ymax[half][oi] = mx;
  }
  __syncthreads();
  if (tid < 128) {
    const float v = fmaxf(ymax[0][tid], ymax[1][tid]) + bo_sum[layer*128 + tid] + b_layer[tid];
    res[(size_t)n * 128 + tid] = v;
  }
}

// ---------------- pairnorm reductions ----------------
__global__ __launch_bounds__(256) void reduce_kernel(const float* __restrict__ res,
                                                     float* __restrict__ partial) {
  __shared__ float col2[128];
  __shared__ float sqs[256];
  const int b = blockIdx.x, tid = threadIdx.x;
  const int c = tid & 127, half = tid >> 7;
  float cs = 0.f, sq = 0.f;
  const int r0 = half * 64;
  for (int r = r0; r < r0 + 64; ++r) {
    const float v = res[((size_t)b * 128 + r) * 128 + c];
    cs += v; sq += v * v;
  }
  if (half) col2[c] = cs;
  sqs[tid] = sq;
  __syncthreads();
  if (!half) partial[b * 129 + c] = cs + col2[c];
  for (int s = 128; s >= 1; s >>= 1) {
    if (tid < s) sqs[tid] += sqs[tid + s];
    __syncthreads();
  }
  if (tid == 0) partial[b * 129 + 128] = sqs[0];
}

__global__ __launch_bounds__(1024) void finalize_kernel(const float* __restrict__ partial,
                                                        float* __restrict__ stats) {
  __shared__ float colsum[8][128];
  __shared__ float sqred[256];
  __shared__ float musq[128];
  const int tid = threadIdx.x;
  const int c = tid & 127, g = tid >> 7;
  float cs = 0.f;
  #pragma unroll 8
  for (int b = g * 32; b < g * 32 + 32; ++b) cs += partial[b * 129 + c];
  colsum[g][c] = cs;
  if (tid < 256) sqred[tid] = partial[tid * 129 + 128];
  __syncthreads();
  if (tid < 128) {
    float m = 0.f;
    #pragma unroll
    for (int g2 = 0; g2 < 8; ++g2) m += colsum[g2][tid];
    m *= (1.f / 32768.f);
    stats[tid] = m;
    musq[tid] = m * m;
  }
  __syncthreads();
  for (int s = 128; s >= 1; s >>= 1) {
    if (tid < s) sqred[tid] += sqred[tid + s];
    if (s <= 64 && tid < s) musq[tid] += musq[tid + s];
    __syncthreads();
  }
  if (tid == 0) {
    const float var = sqred[0] * (1.f / 32768.f) - musq[0];
    stats[128] = 1.f / sqrtf(1e-6f + var);
  }
}

__global__ void final_kernel(const float* __restrict__ res, const float* __restrict__ stats,
                             const float* __restrict__ xf, void* __restrict__ out,
                             const int* __restrict__ flagp) {
  const int idx = blockIdx.x * 256 + threadIdx.x;
  const int nrow = idx >> 7, c = idx & 127;
  float v = fmaxf((res[idx] - stats[c]) * stats[128], 0.f);
  v += xf[(size_t)nrow * XW + c];
  if (c == 127 && (v > 1.f || v < -1.f)) v = 0.f;
  v *= 0.5f;
  if (*flagp) ((__hip_bfloat16*)out)[idx] = __float2bfloat16(v);
  else        ((float*)out)[idx] = v;
}

// ---------------- host ----------------
extern "C" void kernel_launch(void* const* d_in, const int* in_sizes, int n_in,
                              void* d_out, int out_size, void* d_ws, size_t ws_size,
                              hipStream_t stream) {
  (void)in_sizes; (void)n_in; (void)out_size; (void)ws_size;
  char* ws = (char*)d_ws;
  size_t off = 0;
  auto alloc = [&](size_t bytes) -> char* {
    char* p = ws + off;
    off += (bytes + 255) & ~(size_t)255;
    return p;
  };
  int*   flagp = (int*)  alloc(4);
  float* xf    = (float*)alloc((size_t)NN * XW * 4);
  float* W1f   = (float*)alloc(130 * 128 * 4);
  float* b1f   = (float*)alloc(128 * 4);
  float* W2f   = (float*)alloc(128 * 128 * 4);
  float* b2f   = (float*)alloc(128 * 4);
  float* qwf   = (float*)alloc((size_t)225228 * 4);
  float* qbf   = (float*)alloc(1644 * 4);
  float* owf   = (float*)alloc((size_t)75076 * 4);
  float* obf   = (float*)alloc(548 * 4);
  float* Mqk   = (float*)alloc((size_t)4 * 16384 * 4);
  float* Mvo   = (float*)alloc((size_t)4 * 16384 * 4);
  float* cq    = (float*)alloc((size_t)4 * 1233 * 4);
  float* ck    = (float*)alloc((size_t)4 * 1233 * 4);
  float* cvo   = (float*)alloc((size_t)4 * 1152 * 4);
  float* cc    = (float*)alloc((size_t)4 * 81 * 4);
  float* boS   = (float*)alloc((size_t)2 * 128 * 4);
  float* BigW  = (float*)alloc((size_t)2 * 128 * PW * 4);
  float* BigB  = (float*)alloc((size_t)2 * 130 * 676 * 4);
  float* G     = (float*)alloc((size_t)NN * GW * 4);
  float* res   = (float*)alloc((size_t)NN * 128 * 4);
  float* part  = (float*)alloc((size_t)256 * 129 * 4);
  float* st0   = (float*)alloc(132 * 4);
  float* st1   = (float*)alloc(132 * 4);

  const int* edge = (const int*)d_in[1];   // row 0 = src

  detect_kernel<<<1, 64, 0, stream>>>(d_in[0], flagp);

  CvtAll ca;
  {
    const int srcidx[9] = {0, 2, 3, 4, 5, 6, 7, 8, 9};
    float* dsts[9] = {xf, W1f, b1f, W2f, b2f, qwf, qbf, owf, obf};
    const int ns[9] = {NN * 130, 130 * 128, 128, 128 * 128, 128,
                       225228, 1644, 75076, 548};
    int acc = 0;
    for (int i = 0; i < 9; ++i) {
      ca.src[i] = d_in[srcidx[i]];
      ca.dst[i] = dsts[i];
      ca.cum[i] = acc;
      acc += ns[i];
    }
    ca.cum[9] = acc;
  }
  cvt_all_kernel<<<4096, 256, 0, stream>>>(ca, flagp);

  derive_cqck_kernel<<<dim3(5, 4), 256, 0, stream>>>(qwf, qbf, cq, ck);
  derive_rest_kernel<<<dim3(6, 4), 256, 0, stream>>>(qwf, qbf, owf, obf, cq, ck,
                                                     cvo, cc, boS);
  derive_mm_kernel<<<dim3(64, 4), 256, 0, stream>>>(qwf, owf, Mqk, Mvo);
  bigw_kernel<<<(2 * 128 * PW + 255) / 256, 256, 0, stream>>>(qwf, Mqk, Mvo, cq, ck, BigW);
  buildb_kernel<<<dim3((130 * 676 + 255) / 256, 2), 256, 0, stream>>>(W1f, W2f, BigW, BigB);

  for (int l = 0; l < 2; ++l) {
    // G = op(act) @ BigB_l  (single ragged GEMM; pairnorm+relu folded into A for l=1)
    if (l == 0) {
      gemm128_kernel<<<dim3(6, NN / 128), 256, 0, stream>>>(
          xf, BigB, G, NN, 130, GW, XW, 676, GW, nullptr);
    } else {
      gemm128_kernel<<<dim3(6, NN / 128), 256, 0, stream>>>(
          res, BigB + (size_t)130 * 676, G, NN, 128, GW, 128, 676, GW, st0);
    }
    // fused per-node attention + max + bias
    attn_kernel<<<NN, 256, 0, stream>>>(edge, G, cvo, cc, boS,
                                        l ? b2f : b1f, l, res);
    // pairnorm stats
    reduce_kernel<<<256, 256, 0, stream>>>(res, part);
    finalize_kernel<<<1, 1024, 0, stream>>>(part, l ? st1 : st0);
  }
  final_kernel<<<NN * 128 / 256, 256, 0, stream>>>(res, st1, xf, d_out, flagp);
}